// Round 7
// baseline (868.474 us; speedup 1.0000x reference)
//
#include <hip/hip_runtime.h>
#include <hip/hip_bf16.h>
#include <math.h>

// ---------------------------------------------------------------------------
// Nystrom attention layer. Round 7: Round-6 kernels + FIXED workspace layout
// (R5/R6 failures were q/k/v/vt buffer overlap, not numerics).
// b=4, n=4096, d=512, h=8, dh=64, m=256 landmarks, l=16, conv K=33.
// out = attn1 @ (pinv(attn2) @ (attn3 @ v))  (re-associated)
// ---------------------------------------------------------------------------

using bf16x8 = __attribute__((ext_vector_type(8))) short;
using f32x4  = __attribute__((ext_vector_type(4))) float;

static __device__ __forceinline__ f32x4 MFMA16(bf16x8 a, bf16x8 b, f32x4 c) {
    return __builtin_amdgcn_mfma_f32_16x16x32_bf16(a, b, c, 0, 0, 0);
}
static __device__ __forceinline__ unsigned short f2b(float f) {
    union { float f; unsigned u; } x; x.f = f;
    unsigned r = x.u + 0x7FFFu + ((x.u >> 16) & 1u);
    return (unsigned short)(r >> 16);
}
static __device__ __forceinline__ float b2f(unsigned short b) {
    union { unsigned u; float f; } x; x.u = ((unsigned)b) << 16; return x.f;
}

// ---------------- LayerNorm: 16384 rows x 512, bf16 out ----------------
__global__ __launch_bounds__(256) void ln_kernel(const float* __restrict__ x,
                                                 const float* __restrict__ g,
                                                 const float* __restrict__ b,
                                                 unsigned short* __restrict__ xn) {
    int row = blockIdx.x;
    const float* xr = x + (size_t)row * 512;
    int t = threadIdx.x;
    float v0 = xr[t], v1 = xr[t + 256];
    __shared__ float red[4];
    float s = v0 + v1;
#pragma unroll
    for (int off = 32; off; off >>= 1) s += __shfl_down(s, off);
    if ((t & 63) == 0) red[t >> 6] = s;
    __syncthreads();
    float mean = (red[0] + red[1] + red[2] + red[3]) * (1.0f / 512.0f);
    __syncthreads();
    float d0 = v0 - mean, d1 = v1 - mean;
    float q2 = d0 * d0 + d1 * d1;
#pragma unroll
    for (int off = 32; off; off >>= 1) q2 += __shfl_down(q2, off);
    if ((t & 63) == 0) red[t >> 6] = q2;
    __syncthreads();
    float var = (red[0] + red[1] + red[2] + red[3]) * (1.0f / 512.0f);
    float inv = rsqrtf(var + 1e-5f);
    unsigned short* o = xn + (size_t)row * 512;
    o[t]       = f2b(d0 * inv * g[t]       + b[t]);
    o[t + 256] = f2b(d1 * inv * g[t + 256] + b[t + 256]);
}

// ---------------- weight conversion f32 -> bf16 ----------------
__global__ void cvt_kernel(const float* __restrict__ wqkv, const float* __restrict__ wout,
                           unsigned short* __restrict__ wqkvb, unsigned short* __restrict__ woutb) {
    int idx = blockIdx.x * 256 + threadIdx.x;   // 1048576
    if (idx < 786432) wqkvb[idx] = f2b(wqkv[idx]);
    else woutb[idx - 786432] = f2b(wout[idx - 786432]);
}

// ---------------- bf16 MFMA GEMM: C[M,*] = A[M,512] @ Bw[N,512]^T ----------------
template<int MODE>
__global__ __launch_bounds__(256) void gemm_mfma(const unsigned short* __restrict__ A,
                                                 const unsigned short* __restrict__ Bw,
                                                 unsigned short* __restrict__ qb,
                                                 unsigned short* __restrict__ kb,
                                                 unsigned short* __restrict__ vb,
                                                 const float* __restrict__ bias,
                                                 const float* __restrict__ xres,
                                                 float* __restrict__ out) {
    const int K = 512;
    __shared__ unsigned short As[128][40];
    __shared__ unsigned short Bs[128][40];
    int t = threadIdx.x;
    int w = t >> 6, l = t & 63, lr = l & 15, g = l >> 4;
    int wm = w >> 1, wn = w & 1;
    int row0 = blockIdx.x * 128, col0 = blockIdx.y * 128;
    f32x4 acc[4][4];
#pragma unroll
    for (int i = 0; i < 4; ++i)
#pragma unroll
        for (int j = 0; j < 4; ++j) acc[i][j] = (f32x4)0.f;
    int srow = t >> 1, sh = t & 1;
    for (int kt = 0; kt < K; kt += 32) {
        const unsigned short* as = A + (size_t)(row0 + srow) * K + kt + sh * 16;
        *(uint4*)&As[srow][sh * 16]     = *(const uint4*)as;
        *(uint4*)&As[srow][sh * 16 + 8] = *(const uint4*)(as + 8);
        const unsigned short* bs = Bw + (size_t)(col0 + srow) * K + kt + sh * 16;
        *(uint4*)&Bs[srow][sh * 16]     = *(const uint4*)bs;
        *(uint4*)&Bs[srow][sh * 16 + 8] = *(const uint4*)(bs + 8);
        __syncthreads();
        bf16x8 a[4], b[4];
#pragma unroll
        for (int mt = 0; mt < 4; ++mt) a[mt] = *(const bf16x8*)&As[wm * 64 + mt * 16 + lr][g * 8];
#pragma unroll
        for (int nt = 0; nt < 4; ++nt) b[nt] = *(const bf16x8*)&Bs[wn * 64 + nt * 16 + lr][g * 8];
#pragma unroll
        for (int mt = 0; mt < 4; ++mt)
#pragma unroll
            for (int nt = 0; nt < 4; ++nt) acc[mt][nt] = MFMA16(a[mt], b[nt], acc[mt][nt]);
        __syncthreads();
    }
#pragma unroll
    for (int mt = 0; mt < 4; ++mt) {
#pragma unroll
        for (int nt = 0; nt < 4; ++nt) {
#pragma unroll
            for (int r = 0; r < 4; ++r) {
                int row = row0 + wm * 64 + mt * 16 + g * 4 + r;
                int col = col0 + wn * 64 + nt * 16 + lr;
                float val = acc[mt][nt][r];
                if (MODE == 0) {
                    int bb = row >> 12, nn = row & 4095;
                    int which = col >> 9, rem = col & 511;
                    int hh = rem >> 6, dd = rem & 63;
                    size_t di = (((size_t)(bb * 8 + hh)) * 4096 + nn) * 64 + dd;
                    if (which == 0) qb[di] = f2b(val * 0.125f);
                    else if (which == 1) kb[di] = f2b(val);
                    else vb[di] = f2b(val);
                } else {
                    out[(size_t)row * 512 + col] = val + bias[col] + xres[(size_t)row * 512 + col];
                }
            }
        }
    }
}

// ---------------- transpose v_bf -> vt_bf [bh][dh][n] ----------------
__global__ __launch_bounds__(256) void vt_kernel(const unsigned short* __restrict__ vb,
                                                 unsigned short* __restrict__ vtb) {
    int n0 = blockIdx.x * 64, bh = blockIdx.y;
    __shared__ unsigned short tl[64][72];
    int t = threadIdx.x;
#pragma unroll
    for (int u = 0; u < 2; ++u) {
        int cid = t * 2 + u;
        int r = cid >> 3, c8 = (cid & 7) << 3;
        uint4 vv = *(const uint4*)(vb + ((size_t)bh * 4096 + n0 + r) * 64 + c8);
        unsigned short* pv = (unsigned short*)&vv;
#pragma unroll
        for (int i = 0; i < 8; ++i) tl[c8 + i][r] = pv[i];
    }
    __syncthreads();
#pragma unroll
    for (int u = 0; u < 2; ++u) {
        int cid = t * 2 + u;
        int r = cid >> 3, c8 = (cid & 7) << 3;
        *(uint4*)(vtb + ((size_t)bh * 64 + r) * 4096 + n0 + c8) = *(uint4*)&tl[r][c8];
    }
}

// ---------------- landmark means (l=16), f32 + split bf16 outs ----------------
__global__ void landmark_kernel(const unsigned short* __restrict__ q,
                                const unsigned short* __restrict__ k,
                                float* __restrict__ ql, float* __restrict__ kl,
                                unsigned short* __restrict__ qlb, unsigned short* __restrict__ klb,
                                unsigned short* __restrict__ qll, unsigned short* __restrict__ kll) {
    int idx = blockIdx.x * 256 + threadIdx.x;   // 524288
    int dh = idx & 63, mi = (idx >> 6) & 255, bh = idx >> 14;
    size_t base = ((size_t)bh * 4096 + mi * 16) * 64 + dh;
    float sq = 0, sk = 0;
#pragma unroll
    for (int j = 0; j < 16; ++j) { sq += b2f(q[base + (size_t)j * 64]); sk += b2f(k[base + (size_t)j * 64]); }
    sq *= 0.0625f; sk *= 0.0625f;
    ql[idx] = sq; kl[idx] = sk;
    unsigned short qh = f2b(sq), kh = f2b(sk);
    qlb[idx] = qh; klb[idx] = kh;
    qll[idx] = f2b(sq - b2f(qh));
    kll[idx] = f2b(sk - b2f(kh));
}

// ---------------- depthwise conv residual -> outh (f32 [bh][n][dh]) ----------------
__global__ __launch_bounds__(256) void conv_kernel(const unsigned short* __restrict__ v,
                                                   const float* __restrict__ rw,
                                                   float* __restrict__ outh) {
    int idx = blockIdx.x * 256 + threadIdx.x;   // 1048576
    int o = idx & 7, n = (idx >> 3) & 4095, bh = idx >> 15;
    int h = bh & 7;
    const unsigned short* vb = v + (((size_t)bh) << 18) + o * 8;
    float acc[8];
#pragma unroll
    for (int i = 0; i < 8; ++i) acc[i] = 0.f;
#pragma unroll
    for (int tt = 0; tt < 33; ++tt) {
        int j = n + tt - 16;
        if (j >= 0 && j < 4096) {
            uint4 pv = *(const uint4*)(vb + (size_t)j * 64);
            const unsigned short* pp = (const unsigned short*)&pv;
            float wgt = rw[h * 33 + tt];
#pragma unroll
            for (int i = 0; i < 8; ++i) acc[i] = fmaf(wgt, b2f(pp[i]), acc[i]);
        }
    }
    float4 r0, r1;
    r0.x = acc[0]; r0.y = acc[1]; r0.z = acc[2]; r0.w = acc[3];
    r1.x = acc[4]; r1.y = acc[5]; r1.z = acc[6]; r1.w = acc[7];
    *(float4*)(outh + (size_t)idx * 8)     = r0;
    *(float4*)(outh + (size_t)idx * 8 + 4) = r1;
}

// ---------------- attn2 = softmax(ql @ kl^T) via split MFMA, f32 out ----------------
__global__ __launch_bounds__(256) void attn2_mfma(const unsigned short* __restrict__ qlh,
                                                  const unsigned short* __restrict__ qllo,
                                                  const unsigned short* __restrict__ klh,
                                                  const unsigned short* __restrict__ kllo,
                                                  float* __restrict__ a2) {
    int it = blockIdx.x, bh = blockIdx.y;
    __shared__ unsigned short qh_l[64][72], ql_l[64][72];
    __shared__ unsigned short kh_l[128][72], kl_l[128][72];
    int t = threadIdx.x;
    int w = t >> 6, l = t & 63, lr = l & 15, g = l >> 4;
    int i0 = it * 64;
    int srow = t >> 2, sq = t & 3;
    {   // stage q tile (64 rows) hi+lo
        size_t gi = ((size_t)bh * 256 + i0 + srow) * 64 + sq * 16;
        *(uint4*)&qh_l[srow][sq * 16]     = *(const uint4*)(qlh + gi);
        *(uint4*)&qh_l[srow][sq * 16 + 8] = *(const uint4*)(qlh + gi + 8);
        *(uint4*)&ql_l[srow][sq * 16]     = *(const uint4*)(qllo + gi);
        *(uint4*)&ql_l[srow][sq * 16 + 8] = *(const uint4*)(qllo + gi + 8);
    }
    f32x4 p[16];
    float tsum[4] = {0.f, 0.f, 0.f, 0.f};
    bf16x8 ah0, ah1, al0, al1;
#pragma unroll
    for (int ph = 0; ph < 2; ++ph) {
        __syncthreads();    // kh_l reuse barrier (and q visibility on ph 0)
#pragma unroll
        for (int st = 0; st < 2; ++st) {
            int row = st * 64 + srow;
            size_t gi = ((size_t)bh * 256 + ph * 128 + row) * 64 + sq * 16;
            *(uint4*)&kh_l[row][sq * 16]     = *(const uint4*)(klh + gi);
            *(uint4*)&kh_l[row][sq * 16 + 8] = *(const uint4*)(klh + gi + 8);
            *(uint4*)&kl_l[row][sq * 16]     = *(const uint4*)(kllo + gi);
            *(uint4*)&kl_l[row][sq * 16 + 8] = *(const uint4*)(kllo + gi + 8);
        }
        __syncthreads();
        if (ph == 0) {
            ah0 = *(const bf16x8*)&qh_l[w * 16 + lr][g * 8];
            ah1 = *(const bf16x8*)&qh_l[w * 16 + lr][32 + g * 8];
            al0 = *(const bf16x8*)&ql_l[w * 16 + lr][g * 8];
            al1 = *(const bf16x8*)&ql_l[w * 16 + lr][32 + g * 8];
        }
#pragma unroll
        for (int f = 0; f < 8; ++f) {
            bf16x8 bh0 = *(const bf16x8*)&kh_l[f * 16 + lr][g * 8];
            bf16x8 bh1 = *(const bf16x8*)&kh_l[f * 16 + lr][32 + g * 8];
            bf16x8 bl0 = *(const bf16x8*)&kl_l[f * 16 + lr][g * 8];
            bf16x8 bl1 = *(const bf16x8*)&kl_l[f * 16 + lr][32 + g * 8];
            f32x4 s = (f32x4)0.f;
            s = MFMA16(ah0, bh0, s); s = MFMA16(ah1, bh1, s);
            s = MFMA16(ah0, bl0, s); s = MFMA16(ah1, bl1, s);
            s = MFMA16(al0, bh0, s); s = MFMA16(al1, bh1, s);
            f32x4 pe;
#pragma unroll
            for (int r = 0; r < 4; ++r) { pe[r] = __expf(s[r]); tsum[r] += pe[r]; }
            p[ph * 8 + f] = pe;
        }
    }
#pragma unroll
    for (int r = 0; r < 4; ++r) {
#pragma unroll
        for (int m = 1; m < 16; m <<= 1) tsum[r] += __shfl_xor(tsum[r], m);
    }
#pragma unroll
    for (int f = 0; f < 16; ++f) {
#pragma unroll
        for (int r = 0; r < 4; ++r) {
            a2[((size_t)bh * 256 + i0 + w * 16 + g * 4 + r) * 256 + f * 16 + lr] = p[f][r] / tsum[r];
        }
    }
}

// ---------------- max column-sum of attn2 (row-sums are exactly 1) ----------------
__global__ __launch_bounds__(256) void colmax_kernel(const float* __restrict__ a2,
                                                     unsigned* __restrict__ scal) {
    int bh = blockIdx.x, t = threadIdx.x;
    const float* m = a2 + (size_t)bh * 65536;
    float cs = 0;
    for (int i = 0; i < 256; ++i) cs += m[i * 256 + t];
#pragma unroll
    for (int off = 32; off; off >>= 1) cs = fmaxf(cs, __shfl_down(cs, off));
    __shared__ float red[4];
    if ((t & 63) == 0) red[t >> 6] = cs;
    __syncthreads();
    if (t == 0) {
        float mx = fmaxf(fmaxf(red[0], red[1]), fmaxf(red[2], red[3]));
        atomicMax(scal, __float_as_uint(mx));
    }
}

// ---------------- z0 = attn2^T / colsum_max: f32 + split bf16 out ----------------
__global__ __launch_bounds__(256) void z0_split(const float* __restrict__ a2,
                                                const float* __restrict__ scal,
                                                float* __restrict__ zf,
                                                unsigned short* __restrict__ zh,
                                                unsigned short* __restrict__ zl) {
    int bh = blockIdx.z;
    int ib = blockIdx.x * 64, jb = blockIdx.y * 64;
    __shared__ float tl[64][65];
    float c = 1.0f / *scal;
    int t = threadIdx.x;
#pragma unroll
    for (int u = 0; u < 16; ++u) {
        int idx = t + 256 * u;
        int r = idx >> 6, cc = idx & 63;
        tl[r][cc] = a2[(size_t)bh * 65536 + (size_t)(jb + r) * 256 + ib + cc];
    }
    __syncthreads();
#pragma unroll
    for (int u = 0; u < 16; ++u) {
        int idx = t + 256 * u;
        int r = idx >> 6, cc = idx & 63;
        float v = tl[cc][r] * c;
        unsigned short hi = f2b(v);
        size_t di = (size_t)bh * 65536 + (size_t)(ib + r) * 256 + jb + cc;
        zf[di] = v;
        zh[di] = hi;
        zl[di] = f2b(v - b2f(hi));
    }
}

// ---------------- split a2 f32 -> (hi, lo) bf16 ----------------
__global__ void split_kernel(const float* __restrict__ src,
                             unsigned short* __restrict__ dh,
                             unsigned short* __restrict__ dl) {
    int idx4 = (blockIdx.x * 256 + threadIdx.x) * 4;    // 2097152 total
    float4 v = *(const float4*)(src + idx4);
    float vv[4] = {v.x, v.y, v.z, v.w};
    ushort4 h4, l4;
    unsigned short* hp = (unsigned short*)&h4;
    unsigned short* lp = (unsigned short*)&l4;
#pragma unroll
    for (int j = 0; j < 4; ++j) {
        unsigned short hi = f2b(vv[j]);
        hp[j] = hi;
        lp[j] = f2b(vv[j] - b2f(hi));
    }
    *(ushort4*)(dh + idx4) = h4;
    *(ushort4*)(dl + idx4) = l4;
}

// ---------------- split-operand MFMA batched GEMM (pinv loop) ----------------
// 256x256x256 per batch; Df32 = alpha*(A@B) + gamma*Ef32 (f32 carriers);
// split pair (Dh,Dl) written alongside for the next GEMM's MFMA operands.
__global__ __launch_bounds__(256) void bgemm_split2(const unsigned short* __restrict__ Ahg,
                                                    const unsigned short* __restrict__ Alg,
                                                    const unsigned short* __restrict__ Bhg,
                                                    const unsigned short* __restrict__ Blg,
                                                    unsigned short* __restrict__ Dh,
                                                    unsigned short* __restrict__ Dl,
                                                    float* __restrict__ Df,
                                                    const float* __restrict__ Ef,
                                                    float alpha, float gamma) {
    size_t so = (size_t)blockIdx.z * 65536;
    Ahg += so; Alg += so; Bhg += so; Blg += so; Dh += so; Dl += so; Df += so;
    const float* Efp = Ef ? Ef + so : nullptr;
    __shared__ unsigned short Ah[64][40], Al[64][40], Bh2[64][40], Bl2[64][40];
    int t = threadIdx.x;
    int w = t >> 6, l = t & 63, lr = l & 15, g = l >> 4;
    int wm = w >> 1, wn = w & 1;
    int bm = blockIdx.x, bn = blockIdx.y;
    f32x4 acc[2][2];
#pragma unroll
    for (int i = 0; i < 2; ++i)
#pragma unroll
        for (int j = 0; j < 2; ++j) acc[i][j] = (f32x4)0.f;
    int arow = t >> 2, akq = (t & 3) * 8;
    int bkr = t >> 3, bnq = (t & 7) * 8;
    for (int kt = 0; kt < 256; kt += 32) {
        size_t ai = (size_t)(bm * 64 + arow) * 256 + kt + akq;
        *(uint4*)&Ah[arow][akq] = *(const uint4*)(Ahg + ai);
        *(uint4*)&Al[arow][akq] = *(const uint4*)(Alg + ai);
        size_t bi = (size_t)(kt + bkr) * 256 + bn * 64 + bnq;
        uint4 bhv = *(const uint4*)(Bhg + bi);
        uint4 blv = *(const uint4*)(Blg + bi);
        const unsigned short* bhp = (const unsigned short*)&bhv;
        const unsigned short* blp = (const unsigned short*)&blv;
#pragma unroll
        for (int i = 0; i < 8; ++i) {
            Bh2[bnq + i][bkr] = bhp[i];
            Bl2[bnq + i][bkr] = blp[i];
        }
        __syncthreads();
        bf16x8 ah[2], al_[2], bh[2], bl_[2];
#pragma unroll
        for (int mf = 0; mf < 2; ++mf) {
            ah[mf]  = *(const bf16x8*)&Ah[wm * 32 + mf * 16 + lr][g * 8];
            al_[mf] = *(const bf16x8*)&Al[wm * 32 + mf * 16 + lr][g * 8];
        }
#pragma unroll
        for (int nf = 0; nf < 2; ++nf) {
            bh[nf]  = *(const bf16x8*)&Bh2[wn * 32 + nf * 16 + lr][g * 8];
            bl_[nf] = *(const bf16x8*)&Bl2[wn * 32 + nf * 16 + lr][g * 8];
        }
#pragma unroll
        for (int mf = 0; mf < 2; ++mf)
#pragma unroll
            for (int nf = 0; nf < 2; ++nf) {
                acc[mf][nf] = MFMA16(ah[mf], bh[nf], acc[mf][nf]);
                acc[mf][nf] = MFMA16(ah[mf], bl_[nf], acc[mf][nf]);
                acc[mf][nf] = MFMA16(al_[mf], bh[nf], acc[mf][nf]);
            }
        __syncthreads();
    }
#pragma unroll
    for (int mf = 0; mf < 2; ++mf) {
#pragma unroll
        for (int nf = 0; nf < 2; ++nf) {
#pragma unroll
            for (int r = 0; r < 4; ++r) {
                int row = bm * 64 + wm * 32 + mf * 16 + g * 4 + r;
                int col = bn * 64 + wn * 32 + nf * 16 + lr;
                size_t di = (size_t)row * 256 + col;
                float val = alpha * acc[mf][nf][r];
                if (Efp) val = fmaf(gamma, Efp[di], val);
                Df[di] = val;
                unsigned short hi = f2b(val);
                Dh[di] = hi;
                Dl[di] = f2b(val - b2f(hi));
            }
        }
    }
}

// ---------------- w2t = (zc @ a3v)^T as bf16 [bh][dh=64][j=256] ----------------
__global__ __launch_bounds__(256) void bgemm_w2t(const float* __restrict__ A,
                                                 const float* __restrict__ B,
                                                 unsigned short* __restrict__ w2t) {
    const int M = 256, N = 64, K = 256;
    int s = blockIdx.z;
    int bm = blockIdx.x;
    A += (size_t)s * M * K; B += (size_t)s * K * N;
    __shared__ float As[32][67];
    __shared__ float Bs[32][68];
    int t = threadIdx.x;
    int tm = t & 15, tn = t >> 4;
    float acc[4][4];
#pragma unroll
    for (int i = 0; i < 4; ++i)
#pragma unroll
        for (int j = 0; j < 4; ++j) acc[i][j] = 0.f;
    for (int kt = 0; kt < K; kt += 32) {
#pragma unroll
        for (int u = 0; u < 2; ++u) {
            int fid = t + 256 * u;
            int r = fid >> 3, kg = (fid & 7) << 2;
            float4 av = *(const float4*)(A + (size_t)(bm * 64 + r) * K + kt + kg);
            As[kg + 0][r] = av.x; As[kg + 1][r] = av.y; As[kg + 2][r] = av.z; As[kg + 3][r] = av.w;
            int kr = fid >> 4, cg = (fid & 15) << 2;
            if (cg < N) {
                float4 bv = *(const float4*)(B + (size_t)(kt + kr) * N + cg);
                *(float4*)(&Bs[kr][cg]) = bv;
            }
        }
        __syncthreads();
#pragma unroll
        for (int kk = 0; kk < 32; ++kk) {
            float a[4], bb[4];
#pragma unroll
            for (int i = 0; i < 4; ++i) a[i] = As[kk][tm * 4 + i];
#pragma unroll
            for (int j = 0; j < 4; ++j) bb[j] = Bs[kk][(tn & 15) * 4 + j];
#pragma unroll
            for (int i = 0; i < 4; ++i)
#pragma unroll
                for (int j = 0; j < 4; ++j) acc[i][j] = fmaf(a[i], bb[j], acc[i][j]);
        }
        __syncthreads();
    }
    if (tn < 16) {
#pragma unroll
        for (int i = 0; i < 4; ++i) {
            int r = bm * 64 + tm * 4 + i;
#pragma unroll
            for (int j = 0; j < 4; ++j) {
                int c = tn * 4 + j;
                w2t[(size_t)s * 16384 + (size_t)c * 256 + r] = f2b(acc[i][j]);
            }
        }
    }
}

// ---------------- attn3@v fused-softmax MFMA (j-split partials) ----------------
__global__ __launch_bounds__(256) void attn3v_mfma(const unsigned short* __restrict__ qlb,
                                                   const unsigned short* __restrict__ kb,
                                                   const unsigned short* __restrict__ vtb,
                                                   float* __restrict__ num_part,
                                                   float* __restrict__ den_part) {
    int it = blockIdx.x, js = blockIdx.y, bh = blockIdx.z;
    __shared__ unsigned short k_lds[64][72];
    __shared__ unsigned short v_lds[64][72];
    __shared__ unsigned short p_lds[4][16][72];
    int t = threadIdx.x;
    int w = t >> 6, l = t & 63, lr = l & 15, g = l >> 4;
    int i0 = it * 64;
    const unsigned short* qp = qlb + ((size_t)(bh * 256 + i0 + w * 16 + lr)) * 64 + g * 8;
    bf16x8 aq0 = *(const bf16x8*)qp;
    bf16x8 aq1 = *(const bf16x8*)(qp + 32);
    f32x4 acc[4];
#pragma unroll
    for (int i = 0; i < 4; ++i) acc[i] = (f32x4)0.f;
    float dacc[4] = {0.f, 0.f, 0.f, 0.f};
    int srow = t >> 2, sq = t & 3;
    const size_t kbase = ((size_t)bh * 4096 + js * 1024) * 64;
    const size_t vbase = (size_t)bh * 64 * 4096 + js * 1024;
    for (int st = 0; st < 16; ++st) {
        int j0 = st * 64;
        {
            const unsigned short* src = kb + kbase + (size_t)(j0 + srow) * 64 + sq * 16;
            *(uint4*)&k_lds[srow][sq * 16]     = *(const uint4*)src;
            *(uint4*)&k_lds[srow][sq * 16 + 8] = *(const uint4*)(src + 8);
            const unsigned short* sv = vtb + vbase + (size_t)srow * 4096 + j0 + sq * 16;
            *(uint4*)&v_lds[srow][sq * 16]     = *(const uint4*)sv;
            *(uint4*)&v_lds[srow][sq * 16 + 8] = *(const uint4*)(sv + 8);
        }
        __syncthreads();
        f32x4 sacc[4];
#pragma unroll
        for (int jt = 0; jt < 4; ++jt) {
            bf16x8 bk0 = *(const bf16x8*)&k_lds[jt * 16 + lr][g * 8];
            bf16x8 bk1 = *(const bf16x8*)&k_lds[jt * 16 + lr][32 + g * 8];
            sacc[jt] = MFMA16(aq0, bk0, (f32x4)0.f);
            sacc[jt] = MFMA16(aq1, bk1, sacc[jt]);
        }
        float dr[4] = {0.f, 0.f, 0.f, 0.f};
#pragma unroll
        for (int jt = 0; jt < 4; ++jt) {
#pragma unroll
            for (int r = 0; r < 4; ++r) {
                float p = __expf(sacc[jt][r]);
                p_lds[w][g * 4 + r][jt * 16 + lr] = f2b(p);
                dr[r] += p;
            }
        }
#pragma unroll
        for (int r = 0; r < 4; ++r) {
#pragma unroll
            for (int m = 1; m < 16; m <<= 1) dr[r] += __shfl_xor(dr[r], m);
            dacc[r] += dr[r];
        }
        bf16x8 pa0 = *(const bf16x8*)&p_lds[w][lr][g * 8];
        bf16x8 pa1 = *(const bf16x8*)&p_lds[w][lr][32 + g * 8];
#pragma unroll
        for (int dt = 0; dt < 4; ++dt) {
            bf16x8 bv0 = *(const bf16x8*)&v_lds[dt * 16 + lr][g * 8];
            bf16x8 bv1 = *(const bf16x8*)&v_lds[dt * 16 + lr][32 + g * 8];
            acc[dt] = MFMA16(pa0, bv0, acc[dt]);
            acc[dt] = MFMA16(pa1, bv1, acc[dt]);
        }
        __syncthreads();
    }
    size_t obase = (size_t)(js * 32 + bh) * 256 + i0 + w * 16;
#pragma unroll
    for (int dt = 0; dt < 4; ++dt)
#pragma unroll
        for (int r = 0; r < 4; ++r)
            num_part[(obase + g * 4 + r) * 64 + dt * 16 + lr] = acc[dt][r];
    if (lr == 0) {
#pragma unroll
        for (int r = 0; r < 4; ++r) den_part[obase + g * 4 + r] = dacc[r];
    }
}

// ---------------- combine attn3v partials ----------------
__global__ void a3v_combine(const float* __restrict__ num_part,
                            const float* __restrict__ den_part,
                            float* __restrict__ a3v) {
    int idx = blockIdx.x * 256 + threadIdx.x;  // 524288
    int dh = idx & 63;
    int rest = idx >> 6;
    float n = 0, d = 0;
#pragma unroll
    for (int s = 0; s < 4; ++s) {
        n += num_part[((size_t)s * 8192 + rest) * 64 + dh];
        d += den_part[(size_t)s * 8192 + rest];
    }
    a3v[idx] = n / d;
}

// ---------------- attn1 fused-softmax MFMA @ w2t, + conv outh -> outh_bf ----------------
__global__ __launch_bounds__(256) void attn1_mfma(const unsigned short* __restrict__ qb,
                                                  const unsigned short* __restrict__ klb,
                                                  const unsigned short* __restrict__ w2t,
                                                  const float* __restrict__ outh,
                                                  unsigned short* __restrict__ outhb) {
    int it = blockIdx.x, bh = blockIdx.y;
    __shared__ unsigned short k_lds[64][72];
    __shared__ unsigned short v_lds[64][72];
    __shared__ unsigned short p_lds[4][16][72];
    int t = threadIdx.x;
    int w = t >> 6, l = t & 63, lr = l & 15, g = l >> 4;
    int i0 = it * 64;
    const unsigned short* qp = qb + ((size_t)bh * 4096 + i0 + w * 16 + lr) * 64 + g * 8;
    bf16x8 aq0 = *(const bf16x8*)qp;
    bf16x8 aq1 = *(const bf16x8*)(qp + 32);
    f32x4 acc[4];
#pragma unroll
    for (int i = 0; i < 4; ++i) acc[i] = (f32x4)0.f;
    float dacc[4] = {0.f, 0.f, 0.f, 0.f};
    int srow = t >> 2, sq = t & 3;
    for (int st = 0; st < 4; ++st) {
        int j0 = st * 64;
        {
            const unsigned short* src = klb + ((size_t)bh * 256 + j0 + srow) * 64 + sq * 16;
            *(uint4*)&k_lds[srow][sq * 16]     = *(const uint4*)src;
            *(uint4*)&k_lds[srow][sq * 16 + 8] = *(const uint4*)(src + 8);
            const unsigned short* sv = w2t + ((size_t)bh * 64 + srow) * 256 + j0 + sq * 16;
            *(uint4*)&v_lds[srow][sq * 16]     = *(const uint4*)sv;
            *(uint4*)&v_lds[srow][sq * 16 + 8] = *(const uint4*)(sv + 8);
        }
        __syncthreads();
        f32x4 sacc[4];
#pragma unroll
        for (int jt = 0; jt < 4; ++jt) {
            bf16x8 bk0 = *(const bf16x8*)&k_lds[jt * 16 + lr][g * 8];
            bf16x8 bk1 = *(const bf16x8*)&k_lds[jt * 16 + lr][32 + g * 8];
            sacc[jt] = MFMA16(aq0, bk0, (f32x4)0.f);
            sacc[jt] = MFMA16(aq1, bk1, sacc[jt]);
        }
        float dr[4] = {0.f, 0.f, 0.f, 0.f};
#pragma unroll
        for (int jt = 0; jt < 4; ++jt) {
#pragma unroll
            for (int r = 0; r < 4; ++r) {
                float p = __expf(sacc[jt][r]);
                p_lds[w][g * 4 + r][jt * 16 + lr] = f2b(p);
                dr[r] += p;
            }
        }
#pragma unroll
        for (int r = 0; r < 4; ++r) {
#pragma unroll
            for (int m = 1; m < 16; m <<= 1) dr[r] += __shfl_xor(dr[r], m);
            dacc[r] += dr[r];
        }
        bf16x8 pa0 = *(const bf16x8*)&p_lds[w][lr][g * 8];
        bf16x8 pa1 = *(const bf16x8*)&p_lds[w][lr][32 + g * 8];
#pragma unroll
        for (int dt = 0; dt < 4; ++dt) {
            bf16x8 bv0 = *(const bf16x8*)&v_lds[dt * 16 + lr][g * 8];
            bf16x8 bv1 = *(const bf16x8*)&v_lds[dt * 16 + lr][32 + g * 8];
            acc[dt] = MFMA16(pa0, bv0, acc[dt]);
            acc[dt] = MFMA16(pa1, bv1, acc[dt]);
        }
        __syncthreads();
    }
    int bb = bh >> 3, hh = bh & 7;
#pragma unroll
    for (int dt = 0; dt < 4; ++dt) {
#pragma unroll
        for (int r = 0; r < 4; ++r) {
            int row = i0 + w * 16 + g * 4 + r;
            float val = acc[dt][r] / dacc[r]
                      + outh[((size_t)bh * 4096 + row) * 64 + dt * 16 + lr];
            outhb[((size_t)(bb * 4096 + row)) * 512 + hh * 64 + dt * 16 + lr] = f2b(val);
        }
    }
}

// ---------------------------------------------------------------------------
extern "C" void kernel_launch(void* const* d_in, const int* in_sizes, int n_in,
                              void* d_out, int out_size, void* d_ws, size_t ws_size,
                              hipStream_t stream) {
    (void)in_sizes; (void)n_in; (void)out_size; (void)ws_size;
    const float* x     = (const float*)d_in[0];
    const float* ln_g  = (const float*)d_in[1];
    const float* ln_b  = (const float*)d_in[2];
    const float* w_qkv = (const float*)d_in[3];
    const float* w_out = (const float*)d_in[4];
    const float* b_out = (const float*)d_in[5];
    const float* res_w = (const float*)d_in[6];
    float* out = (float*)d_out;

    float* ws = (float*)d_ws;
    // ---- corrected workspace layout (all offsets in f32 slots; 16B-aligned) ----
    unsigned short* xnb = (unsigned short*)ws;            // 8388608 bf16 (dead after qkv gemm)
    //   aliases inside xnb block (4194304 slots), used AFTER xnb is dead:
    float* num_part = ws;                                 // 2097152 (steps 12-13)
    float* den_part = ws + 2097152;                       // 32768
    float* a3v      = ws + 2129920;                       // 524288 (dead after step 14)
    unsigned short* outhb = (unsigned short*)ws;          // 8388608 bf16 (written step 15)
    float* outh = ws + 4194304;                           // 8388608 f32
    float* ql   = ws + 12582912;                          // 524288
    float* kl   = ws + 13107200;                          // 524288
    float* a2   = ws + 13631488;                          // 2097152 (dead after split; reused as Df scratch)
    float* z0f  = ws + 15728640;                          // 2097152
    float* z1f  = ws + 17825792;                          // 2097152
    float* xzf  = ws + 19922944;                          // 2097152
    unsigned* scal = (unsigned*)(ws + 22020096);          // 1 (+3 pad)
    // split pairs: 2097152 bf16 = 1048576 slots each
    unsigned short* a2h = (unsigned short*)(ws + 22020100);
    unsigned short* a2l = (unsigned short*)(ws + 23068676);
    unsigned short* z0h = (unsigned short*)(ws + 24117252);
    unsigned short* z0l = (unsigned short*)(ws + 25165828);
    unsigned short* z1h = (unsigned short*)(ws + 26214404);
    unsigned short* z1l = (unsigned short*)(ws + 27262980);
    unsigned short* xzh = (unsigned short*)(ws + 28311556);
    unsigned short* xzl = (unsigned short*)(ws + 29360132);
    unsigned short* t1h = (unsigned short*)(ws + 30408708);
    unsigned short* t1l = (unsigned short*)(ws + 31457284);
    unsigned short* t2h = (unsigned short*)(ws + 32505860);
    unsigned short* t2l = (unsigned short*)(ws + 33554436);
    // q/k/v/vt: 8388608 bf16 = 4194304 slots each
    unsigned short* qb  = (unsigned short*)(ws + 34603012);
    unsigned short* kb  = (unsigned short*)(ws + 38797316);
    unsigned short* vb  = (unsigned short*)(ws + 42991620);
    unsigned short* vtb = (unsigned short*)(ws + 47185924);
    // small bf16 buffers: 524288 bf16 = 262144 slots each
    unsigned short* qlb   = (unsigned short*)(ws + 51380228);
    unsigned short* klb   = (unsigned short*)(ws + 51642372);
    unsigned short* qll   = (unsigned short*)(ws + 51904516);
    unsigned short* kll   = (unsigned short*)(ws + 52166660);
    unsigned short* wqkvb = (unsigned short*)(ws + 52428804);   // 786432 bf16 = 393216
    unsigned short* woutb = (unsigned short*)(ws + 52822020);   // 262144 bf16 = 131072
    unsigned short* w2tb  = (unsigned short*)(ws + 52953092);   // 524288 bf16 = 262144
    // total: 53215236 f32 slots ~ 213 MB (< R1's proven 222 MB footprint)

    hipMemsetAsync(scal, 0, 4, stream);
    ln_kernel<<<16384, 256, 0, stream>>>(x, ln_g, ln_b, xnb);
    cvt_kernel<<<4096, 256, 0, stream>>>(w_qkv, w_out, wqkvb, woutb);
    gemm_mfma<0><<<dim3(128, 12), 256, 0, stream>>>(xnb, wqkvb, qb, kb, vb, nullptr, nullptr, nullptr);
    vt_kernel<<<dim3(64, 32), 256, 0, stream>>>(vb, vtb);
    landmark_kernel<<<2048, 256, 0, stream>>>(qb, kb, ql, kl, qlb, klb, qll, kll);
    conv_kernel<<<4096, 256, 0, stream>>>(vb, res_w, outh);
    attn2_mfma<<<dim3(4, 32), 256, 0, stream>>>(qlb, qll, klb, kll, a2);
    colmax_kernel<<<32, 256, 0, stream>>>(a2, scal);
    z0_split<<<dim3(4, 4, 32), 256, 0, stream>>>(a2, (const float*)scal, z0f, z0h, z0l);
    split_kernel<<<2048, 256, 0, stream>>>(a2, a2h, a2l);
    unsigned short *zch = z0h, *zcl = z0l, *zah = z1h, *zal = z1l;
    float *zcf = z0f, *zaf = z1f;
    float* dfscratch = a2;   // a2 f32 dead from here on; t1f/t2f are never read
    for (int itr = 0; itr < 6; ++itr) {
        bgemm_split2<<<dim3(4, 4, 32), 256, 0, stream>>>(a2h, a2l, zch, zcl, xzh, xzl, xzf, nullptr, 1.f, 0.f);
        bgemm_split2<<<dim3(4, 4, 32), 256, 0, stream>>>(xzh, xzl, xzh, xzl, t1h, t1l, dfscratch, xzf, -1.f, 7.f);
        bgemm_split2<<<dim3(4, 4, 32), 256, 0, stream>>>(xzh, xzl, t1h, t1l, t2h, t2l, dfscratch, xzf, -1.f, 15.f);
        bgemm_split2<<<dim3(4, 4, 32), 256, 0, stream>>>(zch, zcl, t2h, t2l, zah, zal, zaf, zcf, -0.25f, 3.25f);
        unsigned short* th = zch; zch = zah; zah = th;
        unsigned short* tl2 = zcl; zcl = zal; zal = tl2;
        float* tf = zcf; zcf = zaf; zaf = tf;
    }
    attn3v_mfma<<<dim3(4, 4, 32), 256, 0, stream>>>(qlb, kb, vtb, num_part, den_part);
    a3v_combine<<<2048, 256, 0, stream>>>(num_part, den_part, a3v);
    bgemm_w2t<<<dim3(4, 1, 32), 256, 0, stream>>>(zcf, a3v, w2tb);
    attn1_mfma<<<dim3(64, 32), 256, 0, stream>>>(qb, klb, w2tb, outh, outhb);
    gemm_mfma<1><<<dim3(128, 4), 256, 0, stream>>>(outhb, woutb, nullptr, nullptr, nullptr, b_out, x, out);
}

// Round 8
// 780.555 us; speedup vs baseline: 1.1126x; 1.1126x over previous
//
#include <hip/hip_runtime.h>
#include <hip/hip_bf16.h>
#include <math.h>

// ---------------------------------------------------------------------------
// Nystrom attention layer. Round 8: transpose-free "NAT" pinv chain
// (MFMA computes X@Y^T natively;每 iterate carried in both orientations,
// transpose emitted free in epilogue as 8B stores) + global_load_lds staging
// with XOR-swizzled sources for all GEMMs. Pair-only (hi,lo) bf16 carriers.
// b=4, n=4096, d=512, h=8, dh=64, m=256 landmarks, l=16, conv K=33.
// out = attn1 @ (pinv(attn2) @ (attn3 @ v))  (re-associated)
// ---------------------------------------------------------------------------

using bf16x8 = __attribute__((ext_vector_type(8))) short;
using f32x4  = __attribute__((ext_vector_type(4))) float;

static __device__ __forceinline__ f32x4 MFMA16(bf16x8 a, bf16x8 b, f32x4 c) {
    return __builtin_amdgcn_mfma_f32_16x16x32_bf16(a, b, c, 0, 0, 0);
}
static __device__ __forceinline__ unsigned short f2b(float f) {
    union { float f; unsigned u; } x; x.f = f;
    unsigned r = x.u + 0x7FFFu + ((x.u >> 16) & 1u);
    return (unsigned short)(r >> 16);
}
static __device__ __forceinline__ float b2f(unsigned short b) {
    union { unsigned u; float f; } x; x.u = ((unsigned)b) << 16; return x.f;
}
// 16B-per-lane global->LDS direct copy (lds dest = uniform base + lane*16)
static __device__ __forceinline__ void gload16(const unsigned short* g, void* l) {
    __builtin_amdgcn_global_load_lds(
        (const __attribute__((address_space(1))) unsigned int*)g,
        (__attribute__((address_space(3))) unsigned int*)l, 16, 0, 0);
}

// ---------------- LayerNorm: 16384 rows x 512, bf16 out ----------------
__global__ __launch_bounds__(256) void ln_kernel(const float* __restrict__ x,
                                                 const float* __restrict__ g,
                                                 const float* __restrict__ b,
                                                 unsigned short* __restrict__ xn) {
    int row = blockIdx.x;
    const float* xr = x + (size_t)row * 512;
    int t = threadIdx.x;
    float v0 = xr[t], v1 = xr[t + 256];
    __shared__ float red[4];
    float s = v0 + v1;
#pragma unroll
    for (int off = 32; off; off >>= 1) s += __shfl_down(s, off);
    if ((t & 63) == 0) red[t >> 6] = s;
    __syncthreads();
    float mean = (red[0] + red[1] + red[2] + red[3]) * (1.0f / 512.0f);
    __syncthreads();
    float d0 = v0 - mean, d1 = v1 - mean;
    float q2 = d0 * d0 + d1 * d1;
#pragma unroll
    for (int off = 32; off; off >>= 1) q2 += __shfl_down(q2, off);
    if ((t & 63) == 0) red[t >> 6] = q2;
    __syncthreads();
    float var = (red[0] + red[1] + red[2] + red[3]) * (1.0f / 512.0f);
    float inv = rsqrtf(var + 1e-5f);
    unsigned short* o = xn + (size_t)row * 512;
    o[t]       = f2b(d0 * inv * g[t]       + b[t]);
    o[t + 256] = f2b(d1 * inv * g[t + 256] + b[t + 256]);
}

// ---------------- weight conversion f32 -> bf16 ----------------
__global__ void cvt_kernel(const float* __restrict__ wqkv, const float* __restrict__ wout,
                           unsigned short* __restrict__ wqkvb, unsigned short* __restrict__ woutb) {
    int idx = blockIdx.x * 256 + threadIdx.x;   // 1048576
    if (idx < 786432) wqkvb[idx] = f2b(wqkv[idx]);
    else woutb[idx - 786432] = f2b(wout[idx - 786432]);
}

// ---------------- bf16 MFMA GEMM via global_load_lds: C = A[M,512] @ Bw[N,512]^T ----
// LDS: linear [128 rows][32 cols] bf16 per matrix, chunk-swizzled slot = g^((r>>1)&3).
template<int MODE>
__global__ __launch_bounds__(256) void gemm_mfma(const unsigned short* __restrict__ A,
                                                 const unsigned short* __restrict__ Bw,
                                                 unsigned short* __restrict__ qb,
                                                 unsigned short* __restrict__ kb,
                                                 unsigned short* __restrict__ vb,
                                                 const float* __restrict__ bias,
                                                 const float* __restrict__ xres,
                                                 float* __restrict__ out) {
    __shared__ unsigned char LA[8192];
    __shared__ unsigned char LB[8192];
    int t = threadIdx.x;
    int w = t >> 6, l = t & 63, lr = l & 15, g = l >> 4;
    int wm = w >> 1, wn = w & 1;
    int il = l >> 2;
    int gsrc = (l & 3) ^ ((l >> 3) & 3);
    int row0 = blockIdx.x * 128, col0 = blockIdx.y * 128;
    f32x4 acc[4][4];
#pragma unroll
    for (int i = 0; i < 4; ++i)
#pragma unroll
        for (int j = 0; j < 4; ++j) acc[i][j] = (f32x4)0.f;
    int so = ((lr >> 1) & 3) ^ g;          // swizzled read slot (row base % 16 == 0)
    for (int kt = 0; kt < 512; kt += 32) {
#pragma unroll
        for (int j = 0; j < 2; ++j) {
            int c = w + 4 * j;             // chunk of 16 rows
            gload16(A  + (size_t)(row0 + c * 16 + il) * 512 + kt + gsrc * 8, &LA[c * 1024]);
            gload16(Bw + (size_t)(col0 + c * 16 + il) * 512 + kt + gsrc * 8, &LB[c * 1024]);
        }
        __syncthreads();
        bf16x8 a[4], b[4];
#pragma unroll
        for (int mt = 0; mt < 4; ++mt)
            a[mt] = *(const bf16x8*)&LA[(wm * 64 + mt * 16 + lr) * 64 + so * 16];
#pragma unroll
        for (int nt = 0; nt < 4; ++nt)
            b[nt] = *(const bf16x8*)&LB[(wn * 64 + nt * 16 + lr) * 64 + so * 16];
#pragma unroll
        for (int mt = 0; mt < 4; ++mt)
#pragma unroll
            for (int nt = 0; nt < 4; ++nt) acc[mt][nt] = MFMA16(a[mt], b[nt], acc[mt][nt]);
        __syncthreads();
    }
#pragma unroll
    for (int mt = 0; mt < 4; ++mt) {
#pragma unroll
        for (int nt = 0; nt < 4; ++nt) {
#pragma unroll
            for (int r = 0; r < 4; ++r) {
                int row = row0 + wm * 64 + mt * 16 + g * 4 + r;
                int col = col0 + wn * 64 + nt * 16 + lr;
                float val = acc[mt][nt][r];
                if (MODE == 0) {
                    int bb = row >> 12, nn = row & 4095;
                    int which = col >> 9, rem = col & 511;
                    int hh = rem >> 6, dd = rem & 63;
                    size_t di = (((size_t)(bb * 8 + hh)) * 4096 + nn) * 64 + dd;
                    if (which == 0) qb[di] = f2b(val * 0.125f);
                    else if (which == 1) kb[di] = f2b(val);
                    else vb[di] = f2b(val);
                } else {
                    out[(size_t)row * 512 + col] = val + bias[col] + xres[(size_t)row * 512 + col];
                }
            }
        }
    }
}

// ---------------- transpose v_bf -> vt_bf [bh][dh][n] ----------------
__global__ __launch_bounds__(256) void vt_kernel(const unsigned short* __restrict__ vb,
                                                 unsigned short* __restrict__ vtb) {
    int n0 = blockIdx.x * 64, bh = blockIdx.y;
    __shared__ unsigned short tl[64][72];
    int t = threadIdx.x;
#pragma unroll
    for (int u = 0; u < 2; ++u) {
        int cid = t * 2 + u;
        int r = cid >> 3, c8 = (cid & 7) << 3;
        uint4 vv = *(const uint4*)(vb + ((size_t)bh * 4096 + n0 + r) * 64 + c8);
        unsigned short* pv = (unsigned short*)&vv;
#pragma unroll
        for (int i = 0; i < 8; ++i) tl[c8 + i][r] = pv[i];
    }
    __syncthreads();
#pragma unroll
    for (int u = 0; u < 2; ++u) {
        int cid = t * 2 + u;
        int r = cid >> 3, c8 = (cid & 7) << 3;
        *(uint4*)(vtb + ((size_t)bh * 64 + r) * 4096 + n0 + c8) = *(uint4*)&tl[r][c8];
    }
}

// ---------------- landmark means (l=16), f32 + split bf16 outs ----------------
__global__ void landmark_kernel(const unsigned short* __restrict__ q,
                                const unsigned short* __restrict__ k,
                                float* __restrict__ ql, float* __restrict__ kl,
                                unsigned short* __restrict__ qlb, unsigned short* __restrict__ klb,
                                unsigned short* __restrict__ qll, unsigned short* __restrict__ kll) {
    int idx = blockIdx.x * 256 + threadIdx.x;   // 524288
    int dh = idx & 63, mi = (idx >> 6) & 255, bh = idx >> 14;
    size_t base = ((size_t)bh * 4096 + mi * 16) * 64 + dh;
    float sq = 0, sk = 0;
#pragma unroll
    for (int j = 0; j < 16; ++j) { sq += b2f(q[base + (size_t)j * 64]); sk += b2f(k[base + (size_t)j * 64]); }
    sq *= 0.0625f; sk *= 0.0625f;
    ql[idx] = sq; kl[idx] = sk;
    unsigned short qh = f2b(sq), kh = f2b(sk);
    qlb[idx] = qh; klb[idx] = kh;
    qll[idx] = f2b(sq - b2f(qh));
    kll[idx] = f2b(sk - b2f(kh));
}

// ---------------- depthwise conv residual -> outh (f32 [bh][n][dh]) ----------------
__global__ __launch_bounds__(256) void conv_kernel(const unsigned short* __restrict__ v,
                                                   const float* __restrict__ rw,
                                                   float* __restrict__ outh) {
    int idx = blockIdx.x * 256 + threadIdx.x;   // 1048576
    int o = idx & 7, n = (idx >> 3) & 4095, bh = idx >> 15;
    int h = bh & 7;
    const unsigned short* vb = v + (((size_t)bh) << 18) + o * 8;
    float acc[8];
#pragma unroll
    for (int i = 0; i < 8; ++i) acc[i] = 0.f;
#pragma unroll
    for (int tt = 0; tt < 33; ++tt) {
        int j = n + tt - 16;
        if (j >= 0 && j < 4096) {
            uint4 pv = *(const uint4*)(vb + (size_t)j * 64);
            const unsigned short* pp = (const unsigned short*)&pv;
            float wgt = rw[h * 33 + tt];
#pragma unroll
            for (int i = 0; i < 8; ++i) acc[i] = fmaf(wgt, b2f(pp[i]), acc[i]);
        }
    }
    float4 r0, r1;
    r0.x = acc[0]; r0.y = acc[1]; r0.z = acc[2]; r0.w = acc[3];
    r1.x = acc[4]; r1.y = acc[5]; r1.z = acc[6]; r1.w = acc[7];
    *(float4*)(outh + (size_t)idx * 8)     = r0;
    *(float4*)(outh + (size_t)idx * 8 + 4) = r1;
}

// ---------------- attn2 = softmax(ql @ kl^T) via split MFMA, f32 out ----------------
__global__ __launch_bounds__(256) void attn2_mfma(const unsigned short* __restrict__ qlh,
                                                  const unsigned short* __restrict__ qllo,
                                                  const unsigned short* __restrict__ klh,
                                                  const unsigned short* __restrict__ kllo,
                                                  float* __restrict__ a2) {
    int it = blockIdx.x, bh = blockIdx.y;
    __shared__ unsigned short qh_l[64][72], ql_l[64][72];
    __shared__ unsigned short kh_l[128][72], kl_l[128][72];
    int t = threadIdx.x;
    int w = t >> 6, l = t & 63, lr = l & 15, g = l >> 4;
    int i0 = it * 64;
    int srow = t >> 2, sq = t & 3;
    {
        size_t gi = ((size_t)bh * 256 + i0 + srow) * 64 + sq * 16;
        *(uint4*)&qh_l[srow][sq * 16]     = *(const uint4*)(qlh + gi);
        *(uint4*)&qh_l[srow][sq * 16 + 8] = *(const uint4*)(qlh + gi + 8);
        *(uint4*)&ql_l[srow][sq * 16]     = *(const uint4*)(qllo + gi);
        *(uint4*)&ql_l[srow][sq * 16 + 8] = *(const uint4*)(qllo + gi + 8);
    }
    f32x4 p[16];
    float tsum[4] = {0.f, 0.f, 0.f, 0.f};
    bf16x8 ah0, ah1, al0, al1;
#pragma unroll
    for (int ph = 0; ph < 2; ++ph) {
        __syncthreads();
#pragma unroll
        for (int st = 0; st < 2; ++st) {
            int row = st * 64 + srow;
            size_t gi = ((size_t)bh * 256 + ph * 128 + row) * 64 + sq * 16;
            *(uint4*)&kh_l[row][sq * 16]     = *(const uint4*)(klh + gi);
            *(uint4*)&kh_l[row][sq * 16 + 8] = *(const uint4*)(klh + gi + 8);
            *(uint4*)&kl_l[row][sq * 16]     = *(const uint4*)(kllo + gi);
            *(uint4*)&kl_l[row][sq * 16 + 8] = *(const uint4*)(kllo + gi + 8);
        }
        __syncthreads();
        if (ph == 0) {
            ah0 = *(const bf16x8*)&qh_l[w * 16 + lr][g * 8];
            ah1 = *(const bf16x8*)&qh_l[w * 16 + lr][32 + g * 8];
            al0 = *(const bf16x8*)&ql_l[w * 16 + lr][g * 8];
            al1 = *(const bf16x8*)&ql_l[w * 16 + lr][32 + g * 8];
        }
#pragma unroll
        for (int f = 0; f < 8; ++f) {
            bf16x8 bh0 = *(const bf16x8*)&kh_l[f * 16 + lr][g * 8];
            bf16x8 bh1 = *(const bf16x8*)&kh_l[f * 16 + lr][32 + g * 8];
            bf16x8 bl0 = *(const bf16x8*)&kl_l[f * 16 + lr][g * 8];
            bf16x8 bl1 = *(const bf16x8*)&kl_l[f * 16 + lr][32 + g * 8];
            f32x4 s = (f32x4)0.f;
            s = MFMA16(ah0, bh0, s); s = MFMA16(ah1, bh1, s);
            s = MFMA16(ah0, bl0, s); s = MFMA16(ah1, bl1, s);
            s = MFMA16(al0, bh0, s); s = MFMA16(al1, bh1, s);
            f32x4 pe;
#pragma unroll
            for (int r = 0; r < 4; ++r) { pe[r] = __expf(s[r]); tsum[r] += pe[r]; }
            p[ph * 8 + f] = pe;
        }
    }
#pragma unroll
    for (int r = 0; r < 4; ++r) {
#pragma unroll
        for (int m = 1; m < 16; m <<= 1) tsum[r] += __shfl_xor(tsum[r], m);
    }
#pragma unroll
    for (int f = 0; f < 16; ++f) {
#pragma unroll
        for (int r = 0; r < 4; ++r) {
            a2[((size_t)bh * 256 + i0 + w * 16 + g * 4 + r) * 256 + f * 16 + lr] = p[f][r] / tsum[r];
        }
    }
}

// ---------------- max column-sum of attn2 ----------------
__global__ __launch_bounds__(256) void colmax_kernel(const float* __restrict__ a2,
                                                     unsigned* __restrict__ scal) {
    int bh = blockIdx.x, t = threadIdx.x;
    const float* m = a2 + (size_t)bh * 65536;
    float cs = 0;
    for (int i = 0; i < 256; ++i) cs += m[i * 256 + t];
#pragma unroll
    for (int off = 32; off; off >>= 1) cs = fmaxf(cs, __shfl_down(cs, off));
    __shared__ float red[4];
    if ((t & 63) == 0) red[t >> 6] = cs;
    __syncthreads();
    if (t == 0) {
        float mx = fmaxf(fmaxf(red[0], red[1]), fmaxf(red[2], red[3]));
        atomicMax(scal, __float_as_uint(mx));
    }
}

// ---------------- a2 pair + zT0 pair = split(a2), split(a2/scal) ----------------
__global__ void split_scale_kernel(const float* __restrict__ src, const float* __restrict__ scal,
                                   unsigned short* __restrict__ a2h, unsigned short* __restrict__ a2l,
                                   unsigned short* __restrict__ zth, unsigned short* __restrict__ ztl) {
    float c = 1.0f / *scal;
    int idx4 = (blockIdx.x * 256 + threadIdx.x) * 4;    // 2097152 total
    float4 v = *(const float4*)(src + idx4);
    float vv[4] = {v.x, v.y, v.z, v.w};
    ushort4 h4, l4, sh4, sl4;
    unsigned short* hp = (unsigned short*)&h4;  unsigned short* lp = (unsigned short*)&l4;
    unsigned short* shp = (unsigned short*)&sh4; unsigned short* slp = (unsigned short*)&sl4;
#pragma unroll
    for (int j = 0; j < 4; ++j) {
        unsigned short hi = f2b(vv[j]);
        hp[j] = hi; lp[j] = f2b(vv[j] - b2f(hi));
        float sv = vv[j] * c;
        unsigned short shi = f2b(sv);
        shp[j] = shi; slp[j] = f2b(sv - b2f(shi));
    }
    *(ushort4*)(a2h + idx4) = h4;  *(ushort4*)(a2l + idx4) = l4;
    *(ushort4*)(zth + idx4) = sh4; *(ushort4*)(ztl + idx4) = sl4;
}

// ---------------- z0 pair = split(a2^T / scal) (tiled transpose) ----------------
__global__ __launch_bounds__(256) void z0pair_kernel(const float* __restrict__ a2,
                                                     const float* __restrict__ scal,
                                                     unsigned short* __restrict__ zh,
                                                     unsigned short* __restrict__ zl) {
    int bh = blockIdx.z;
    int ib = blockIdx.x * 64, jb = blockIdx.y * 64;
    __shared__ float tl[64][65];
    float c = 1.0f / *scal;
    int t = threadIdx.x;
#pragma unroll
    for (int u = 0; u < 16; ++u) {
        int idx = t + 256 * u;
        int r = idx >> 6, cc = idx & 63;
        tl[r][cc] = a2[(size_t)bh * 65536 + (size_t)(jb + r) * 256 + ib + cc];
    }
    __syncthreads();
#pragma unroll
    for (int u = 0; u < 16; ++u) {
        int idx = t + 256 * u;
        int r = idx >> 6, cc = idx & 63;
        float v = tl[cc][r] * c;
        unsigned short hi = f2b(v);
        size_t di = (size_t)bh * 65536 + (size_t)(ib + r) * 256 + jb + cc;
        zh[di] = hi;
        zl[di] = f2b(v - b2f(hi));
    }
}

// ---------------- NAT batched GEMM: D = alpha*(X @ Y^T) + gamma*(Eh+El) ----------------
// X,Y row-major split pairs, staged via global_load_lds (swizzled source chunks).
// WD: write D pair (or single bf16 if SGL); WDT: write D^T pair (8B stores).
template<int WD, int WDT, int SGL>
__global__ __launch_bounds__(256) void bgemm_nat(
        const unsigned short* __restrict__ Xh, const unsigned short* __restrict__ Xl,
        const unsigned short* __restrict__ Yh, const unsigned short* __restrict__ Yl,
        unsigned short* __restrict__ Dh, unsigned short* __restrict__ Dl,
        unsigned short* __restrict__ DTh, unsigned short* __restrict__ DTl,
        const unsigned short* __restrict__ Eh, const unsigned short* __restrict__ El,
        float alpha, float gamma,
        unsigned int sX, unsigned int sY, unsigned int sD, unsigned int sDT) {
    int s = blockIdx.z;
    const unsigned short* Xhp = Xh + (size_t)s * sX;
    const unsigned short* Xlp = Xl + (size_t)s * sX;
    const unsigned short* Yhp = Yh + (size_t)s * sY;
    const unsigned short* Ylp = Yl + (size_t)s * sY;
    const unsigned short* Ehp = Eh ? Eh + (size_t)s * 65536 : nullptr;
    const unsigned short* Elp = El ? El + (size_t)s * 65536 : nullptr;
    __shared__ unsigned char LXh[4096], LXl[4096], LYh[4096], LYl[4096];
    int t = threadIdx.x;
    int w = t >> 6, l = t & 63, lr = l & 15, g = l >> 4;
    int wm = w >> 1, wn = w & 1;
    int il = l >> 2;
    int gsrc = (l & 3) ^ ((l >> 3) & 3);
    int bm = blockIdx.x, bn = blockIdx.y;
    f32x4 acc[2][2];
#pragma unroll
    for (int i = 0; i < 2; ++i)
#pragma unroll
        for (int j = 0; j < 2; ++j) acc[i][j] = (f32x4)0.f;
    int so = ((lr >> 1) & 3) ^ g;
    size_t xro = (size_t)(bm * 64 + w * 16 + il) * 256;
    size_t yro = (size_t)(bn * 64 + w * 16 + il) * 256;
    for (int kt = 0; kt < 256; kt += 32) {
        gload16(Xhp + xro + kt + gsrc * 8, &LXh[w * 1024]);
        gload16(Xlp + xro + kt + gsrc * 8, &LXl[w * 1024]);
        gload16(Yhp + yro + kt + gsrc * 8, &LYh[w * 1024]);
        gload16(Ylp + yro + kt + gsrc * 8, &LYl[w * 1024]);
        __syncthreads();
        bf16x8 xh[2], xl_[2], yh[2], yl_[2];
#pragma unroll
        for (int mf = 0; mf < 2; ++mf) {
            int off = (wm * 32 + mf * 16 + lr) * 64 + so * 16;
            xh[mf]  = *(const bf16x8*)&LXh[off];
            xl_[mf] = *(const bf16x8*)&LXl[off];
        }
#pragma unroll
        for (int nf = 0; nf < 2; ++nf) {
            int off = (wn * 32 + nf * 16 + lr) * 64 + so * 16;
            yh[nf]  = *(const bf16x8*)&LYh[off];
            yl_[nf] = *(const bf16x8*)&LYl[off];
        }
#pragma unroll
        for (int mf = 0; mf < 2; ++mf)
#pragma unroll
            for (int nf = 0; nf < 2; ++nf) {
                acc[mf][nf] = MFMA16(xh[mf], yh[nf], acc[mf][nf]);
                acc[mf][nf] = MFMA16(xh[mf], yl_[nf], acc[mf][nf]);
                acc[mf][nf] = MFMA16(xl_[mf], yh[nf], acc[mf][nf]);
            }
        __syncthreads();
    }
    size_t dbase = (size_t)s * sD;
    size_t tbase = (size_t)s * sDT;
#pragma unroll
    for (int mf = 0; mf < 2; ++mf) {
#pragma unroll
        for (int nf = 0; nf < 2; ++nf) {
            int rb = bm * 64 + wm * 32 + mf * 16 + g * 4;
            int col = bn * 64 + wn * 32 + nf * 16 + lr;
            float v4[4];
#pragma unroll
            for (int r = 0; r < 4; ++r) {
                float val = alpha * acc[mf][nf][r];
                if (Ehp) {
                    size_t ei = (size_t)(rb + r) * 256 + col;
                    val = fmaf(gamma, b2f(Ehp[ei]) + b2f(Elp[ei]), val);
                }
                v4[r] = val;
            }
            if (WD) {
#pragma unroll
                for (int r = 0; r < 4; ++r) {
                    size_t di = dbase + (size_t)(rb + r) * 256 + col;
                    unsigned short hi = f2b(v4[r]);
                    Dh[di] = hi;
                    if (!SGL) Dl[di] = f2b(v4[r] - b2f(hi));
                }
            }
            if (WDT) {
                ushort4 hh, ll;
                unsigned short* hp = (unsigned short*)&hh;
                unsigned short* lp = (unsigned short*)&ll;
#pragma unroll
                for (int r = 0; r < 4; ++r) {
                    unsigned short hi = f2b(v4[r]);
                    hp[r] = hi;
                    lp[r] = f2b(v4[r] - b2f(hi));
                }
                size_t ti = tbase + (size_t)col * 256 + rb;
                *(ushort4*)(DTh + ti) = hh;
                *(ushort4*)(DTl + ti) = ll;
            }
        }
    }
}

// ---------------- attn3@v fused-softmax MFMA (j-split partials) ----------------
__global__ __launch_bounds__(256) void attn3v_mfma(const unsigned short* __restrict__ qlb,
                                                   const unsigned short* __restrict__ kb,
                                                   const unsigned short* __restrict__ vtb,
                                                   float* __restrict__ num_part,
                                                   float* __restrict__ den_part) {
    int it = blockIdx.x, js = blockIdx.y, bh = blockIdx.z;
    __shared__ unsigned short k_lds[64][72];
    __shared__ unsigned short v_lds[64][72];
    __shared__ unsigned short p_lds[4][16][72];
    int t = threadIdx.x;
    int w = t >> 6, l = t & 63, lr = l & 15, g = l >> 4;
    int i0 = it * 64;
    const unsigned short* qp = qlb + ((size_t)(bh * 256 + i0 + w * 16 + lr)) * 64 + g * 8;
    bf16x8 aq0 = *(const bf16x8*)qp;
    bf16x8 aq1 = *(const bf16x8*)(qp + 32);
    f32x4 acc[4];
#pragma unroll
    for (int i = 0; i < 4; ++i) acc[i] = (f32x4)0.f;
    float dacc[4] = {0.f, 0.f, 0.f, 0.f};
    int srow = t >> 2, sq = t & 3;
    const size_t kbase = ((size_t)bh * 4096 + js * 1024) * 64;
    const size_t vbase = (size_t)bh * 64 * 4096 + js * 1024;
    for (int st = 0; st < 16; ++st) {
        int j0 = st * 64;
        {
            const unsigned short* src = kb + kbase + (size_t)(j0 + srow) * 64 + sq * 16;
            *(uint4*)&k_lds[srow][sq * 16]     = *(const uint4*)src;
            *(uint4*)&k_lds[srow][sq * 16 + 8] = *(const uint4*)(src + 8);
            const unsigned short* sv = vtb + vbase + (size_t)srow * 4096 + j0 + sq * 16;
            *(uint4*)&v_lds[srow][sq * 16]     = *(const uint4*)sv;
            *(uint4*)&v_lds[srow][sq * 16 + 8] = *(const uint4*)(sv + 8);
        }
        __syncthreads();
        f32x4 sacc[4];
#pragma unroll
        for (int jt = 0; jt < 4; ++jt) {
            bf16x8 bk0 = *(const bf16x8*)&k_lds[jt * 16 + lr][g * 8];
            bf16x8 bk1 = *(const bf16x8*)&k_lds[jt * 16 + lr][32 + g * 8];
            sacc[jt] = MFMA16(aq0, bk0, (f32x4)0.f);
            sacc[jt] = MFMA16(aq1, bk1, sacc[jt]);
        }
        float dr[4] = {0.f, 0.f, 0.f, 0.f};
#pragma unroll
        for (int jt = 0; jt < 4; ++jt) {
#pragma unroll
            for (int r = 0; r < 4; ++r) {
                float p = __expf(sacc[jt][r]);
                p_lds[w][g * 4 + r][jt * 16 + lr] = f2b(p);
                dr[r] += p;
            }
        }
#pragma unroll
        for (int r = 0; r < 4; ++r) {
#pragma unroll
            for (int m = 1; m < 16; m <<= 1) dr[r] += __shfl_xor(dr[r], m);
            dacc[r] += dr[r];
        }
        bf16x8 pa0 = *(const bf16x8*)&p_lds[w][lr][g * 8];
        bf16x8 pa1 = *(const bf16x8*)&p_lds[w][lr][32 + g * 8];
#pragma unroll
        for (int dt = 0; dt < 4; ++dt) {
            bf16x8 bv0 = *(const bf16x8*)&v_lds[dt * 16 + lr][g * 8];
            bf16x8 bv1 = *(const bf16x8*)&v_lds[dt * 16 + lr][32 + g * 8];
            acc[dt] = MFMA16(pa0, bv0, acc[dt]);
            acc[dt] = MFMA16(pa1, bv1, acc[dt]);
        }
        __syncthreads();
    }
    size_t obase = (size_t)(js * 32 + bh) * 256 + i0 + w * 16;
#pragma unroll
    for (int dt = 0; dt < 4; ++dt)
#pragma unroll
        for (int r = 0; r < 4; ++r)
            num_part[(obase + g * 4 + r) * 64 + dt * 16 + lr] = acc[dt][r];
    if (lr == 0) {
#pragma unroll
        for (int r = 0; r < 4; ++r) den_part[obase + g * 4 + r] = dacc[r];
    }
}

// ---------------- combine attn3v partials -> a3v^T pair [bh][64][256] ----------------
__global__ void a3v_combine(const float* __restrict__ num_part,
                            const float* __restrict__ den_part,
                            unsigned short* __restrict__ th,
                            unsigned short* __restrict__ tlo) {
    int idx = blockIdx.x * 256 + threadIdx.x;  // 524288 = bh*16384 + dh*256 + i
    int i = idx & 255, dh = (idx >> 8) & 63, bh = idx >> 14;
    int rest = bh * 256 + i;
    float n = 0, d = 0;
#pragma unroll
    for (int s = 0; s < 4; ++s) {
        n += num_part[((size_t)s * 8192 + rest) * 64 + dh];
        d += den_part[(size_t)s * 8192 + rest];
    }
    float v = n / d;
    unsigned short hi = f2b(v);
    th[idx] = hi;
    tlo[idx] = f2b(v - b2f(hi));
}

// ---------------- attn1 fused-softmax MFMA @ w2t, + conv outh -> outh_bf ----------------
__global__ __launch_bounds__(256) void attn1_mfma(const unsigned short* __restrict__ qb,
                                                  const unsigned short* __restrict__ klb,
                                                  const unsigned short* __restrict__ w2t,
                                                  const float* __restrict__ outh,
                                                  unsigned short* __restrict__ outhb) {
    int it = blockIdx.x, bh = blockIdx.y;
    __shared__ unsigned short k_lds[64][72];
    __shared__ unsigned short v_lds[64][72];
    __shared__ unsigned short p_lds[4][16][72];
    int t = threadIdx.x;
    int w = t >> 6, l = t & 63, lr = l & 15, g = l >> 4;
    int i0 = it * 64;
    const unsigned short* qp = qb + ((size_t)bh * 4096 + i0 + w * 16 + lr) * 64 + g * 8;
    bf16x8 aq0 = *(const bf16x8*)qp;
    bf16x8 aq1 = *(const bf16x8*)(qp + 32);
    f32x4 acc[4];
#pragma unroll
    for (int i = 0; i < 4; ++i) acc[i] = (f32x4)0.f;
    float dacc[4] = {0.f, 0.f, 0.f, 0.f};
    int srow = t >> 2, sq = t & 3;
    for (int st = 0; st < 4; ++st) {
        int j0 = st * 64;
        {
            const unsigned short* src = klb + ((size_t)bh * 256 + j0 + srow) * 64 + sq * 16;
            *(uint4*)&k_lds[srow][sq * 16]     = *(const uint4*)src;
            *(uint4*)&k_lds[srow][sq * 16 + 8] = *(const uint4*)(src + 8);
            const unsigned short* sv = w2t + ((size_t)bh * 64 + srow) * 256 + j0 + sq * 16;
            *(uint4*)&v_lds[srow][sq * 16]     = *(const uint4*)sv;
            *(uint4*)&v_lds[srow][sq * 16 + 8] = *(const uint4*)(sv + 8);
        }
        __syncthreads();
        f32x4 sacc[4];
#pragma unroll
        for (int jt = 0; jt < 4; ++jt) {
            bf16x8 bk0 = *(const bf16x8*)&k_lds[jt * 16 + lr][g * 8];
            bf16x8 bk1 = *(const bf16x8*)&k_lds[jt * 16 + lr][32 + g * 8];
            sacc[jt] = MFMA16(aq0, bk0, (f32x4)0.f);
            sacc[jt] = MFMA16(aq1, bk1, sacc[jt]);
        }
        float dr[4] = {0.f, 0.f, 0.f, 0.f};
#pragma unroll
        for (int jt = 0; jt < 4; ++jt) {
#pragma unroll
            for (int r = 0; r < 4; ++r) {
                float p = __expf(sacc[jt][r]);
                p_lds[w][g * 4 + r][jt * 16 + lr] = f2b(p);
                dr[r] += p;
            }
        }
#pragma unroll
        for (int r = 0; r < 4; ++r) {
#pragma unroll
            for (int m = 1; m < 16; m <<= 1) dr[r] += __shfl_xor(dr[r], m);
            dacc[r] += dr[r];
        }
        bf16x8 pa0 = *(const bf16x8*)&p_lds[w][lr][g * 8];
        bf16x8 pa1 = *(const bf16x8*)&p_lds[w][lr][32 + g * 8];
#pragma unroll
        for (int dt = 0; dt < 4; ++dt) {
            bf16x8 bv0 = *(const bf16x8*)&v_lds[dt * 16 + lr][g * 8];
            bf16x8 bv1 = *(const bf16x8*)&v_lds[dt * 16 + lr][32 + g * 8];
            acc[dt] = MFMA16(pa0, bv0, acc[dt]);
            acc[dt] = MFMA16(pa1, bv1, acc[dt]);
        }
        __syncthreads();
    }
    int bb = bh >> 3, hh = bh & 7;
#pragma unroll
    for (int dt = 0; dt < 4; ++dt) {
#pragma unroll
        for (int r = 0; r < 4; ++r) {
            int row = i0 + w * 16 + g * 4 + r;
            float val = acc[dt][r] / dacc[r]
                      + outh[((size_t)bh * 4096 + row) * 64 + dt * 16 + lr];
            outhb[((size_t)(bb * 4096 + row)) * 512 + hh * 64 + dt * 16 + lr] = f2b(val);
        }
    }
}

// ---------------------------------------------------------------------------
extern "C" void kernel_launch(void* const* d_in, const int* in_sizes, int n_in,
                              void* d_out, int out_size, void* d_ws, size_t ws_size,
                              hipStream_t stream) {
    (void)in_sizes; (void)n_in; (void)out_size; (void)ws_size;
    const float* x     = (const float*)d_in[0];
    const float* ln_g  = (const float*)d_in[1];
    const float* ln_b  = (const float*)d_in[2];
    const float* w_qkv = (const float*)d_in[3];
    const float* w_out = (const float*)d_in[4];
    const float* b_out = (const float*)d_in[5];
    const float* res_w = (const float*)d_in[6];
    float* out = (float*)d_out;

    float* ws = (float*)d_ws;
    // region A [0, 4194304): xnb -> num/den/a3vT -> outhb (sequential lifetimes)
    unsigned short* xnb = (unsigned short*)ws;
    float* num_part = ws;                                  // 2097152
    float* den_part = ws + 2097152;                        // 32768
    unsigned short* a3vTh = (unsigned short*)(ws + 2129920);  // 524288 bf16
    unsigned short* a3vTl = (unsigned short*)(ws + 2392064);
    unsigned short* outhb = (unsigned short*)ws;           // 8388608 bf16
    float* outh = ws + 4194304;                            // 8388608 f32
    float* ql   = ws + 12582912;                           // 524288
    float* kl   = ws + 13107200;                           // 524288
    float* a2f  = ws + 13631488;                           // 2097152
    unsigned* scal = (unsigned*)(ws + 15728640);
    // pair buffers: 2097152 bf16 = 1048576 slots each
    unsigned short* a2h  = (unsigned short*)(ws + 15728648);
    unsigned short* a2l  = (unsigned short*)(ws + 16777224);
    unsigned short* zAh  = (unsigned short*)(ws + 17825800);
    unsigned short* zAl  = (unsigned short*)(ws + 18874376);
    unsigned short* zAth = (unsigned short*)(ws + 19922952);
    unsigned short* zAtl = (unsigned short*)(ws + 20971528);
    unsigned short* zBh  = (unsigned short*)(ws + 22020104);
    unsigned short* zBl  = (unsigned short*)(ws + 23068680);
    unsigned short* zBth = (unsigned short*)(ws + 24117256);
    unsigned short* zBtl = (unsigned short*)(ws + 25165832);
    unsigned short* xzh  = (unsigned short*)(ws + 26214408);
    unsigned short* xzl  = (unsigned short*)(ws + 27262984);
    unsigned short* xzth = (unsigned short*)(ws + 28311560);
    unsigned short* xztl = (unsigned short*)(ws + 29360136);
    unsigned short* t1th = (unsigned short*)(ws + 30408712);
    unsigned short* t1tl = (unsigned short*)(ws + 31457288);
    unsigned short* t2th = (unsigned short*)(ws + 32505864);
    unsigned short* t2tl = (unsigned short*)(ws + 33554440);
    // q/k/v/vt: 8388608 bf16 = 4194304 slots each
    unsigned short* qb  = (unsigned short*)(ws + 34603016);
    unsigned short* kb  = (unsigned short*)(ws + 38797320);
    unsigned short* vb  = (unsigned short*)(ws + 42991624);
    unsigned short* vtb = (unsigned short*)(ws + 47185928);
    unsigned short* qlb = (unsigned short*)(ws + 51380232);   // 524288 bf16 each
    unsigned short* klb = (unsigned short*)(ws + 51642376);
    unsigned short* qll = (unsigned short*)(ws + 51904520);
    unsigned short* kll = (unsigned short*)(ws + 52166664);
    unsigned short* wqkvb = (unsigned short*)(ws + 52428808); // 786432 bf16
    unsigned short* woutb = (unsigned short*)(ws + 52822024); // 262144 bf16
    unsigned short* w2tb  = (unsigned short*)(ws + 52953096); // 524288 bf16
    // total 53215240 f32 slots ~ 213 MB

    const unsigned int S = 65536u;
    hipMemsetAsync(scal, 0, 4, stream);
    ln_kernel<<<16384, 256, 0, stream>>>(x, ln_g, ln_b, xnb);
    cvt_kernel<<<4096, 256, 0, stream>>>(w_qkv, w_out, wqkvb, woutb);
    gemm_mfma<0><<<dim3(128, 12), 256, 0, stream>>>(xnb, wqkvb, qb, kb, vb, nullptr, nullptr, nullptr);
    vt_kernel<<<dim3(64, 32), 256, 0, stream>>>(vb, vtb);
    landmark_kernel<<<2048, 256, 0, stream>>>(qb, kb, ql, kl, qlb, klb, qll, kll);
    conv_kernel<<<4096, 256, 0, stream>>>(vb, res_w, outh);
    attn2_mfma<<<dim3(4, 32), 256, 0, stream>>>(qlb, qll, klb, kll, a2f);
    colmax_kernel<<<32, 256, 0, stream>>>(a2f, scal);
    split_scale_kernel<<<2048, 256, 0, stream>>>(a2f, (const float*)scal, a2h, a2l, zAth, zAtl);
    z0pair_kernel<<<dim3(4, 4, 32), 256, 0, stream>>>(a2f, (const float*)scal, zAh, zAl);
    unsigned short *zh = zAh, *zl = zAl, *zth = zAth, *ztl = zAtl;
    unsigned short *nh = zBh, *nl = zBl, *nth = zBth, *ntl = zBtl;
    for (int itr = 0; itr < 6; ++itr) {
        bgemm_nat<1, 1, 0><<<dim3(4, 4, 32), 256, 0, stream>>>(
            a2h, a2l, zth, ztl, xzh, xzl, xzth, xztl, nullptr, nullptr, 1.f, 0.f, S, S, S, S);
        bgemm_nat<0, 1, 0><<<dim3(4, 4, 32), 256, 0, stream>>>(
            xzh, xzl, xzth, xztl, nullptr, nullptr, t1th, t1tl, xzh, xzl, -1.f, 7.f, S, S, S, S);
        bgemm_nat<0, 1, 0><<<dim3(4, 4, 32), 256, 0, stream>>>(
            xzh, xzl, t1th, t1tl, nullptr, nullptr, t2th, t2tl, xzh, xzl, -1.f, 15.f, S, S, S, S);
        bgemm_nat<1, 1, 0><<<dim3(4, 4, 32), 256, 0, stream>>>(
            zh, zl, t2th, t2tl, nh, nl, nth, ntl, zh, zl, -0.25f, 3.25f, S, S, S, S);
        unsigned short* tp;
        tp = zh; zh = nh; nh = tp;   tp = zl; zl = nl; nl = tp;
        tp = zth; zth = nth; nth = tp; tp = ztl; ztl = ntl; ntl = tp;
    }
    attn3v_mfma<<<dim3(4, 4, 32), 256, 0, stream>>>(qlb, kb, vtb, num_part, den_part);
    a3v_combine<<<2048, 256, 0, stream>>>(num_part, den_part, a3vTh, a3vTl);
    bgemm_nat<1, 0, 1><<<dim3(1, 4, 32), 256, 0, stream>>>(
        a3vTh, a3vTl, zh, zl, w2tb, nullptr, nullptr, nullptr, nullptr, nullptr,
        1.f, 0.f, 16384u, S, 16384u, S);
    attn1_mfma<<<dim3(64, 32), 256, 0, stream>>>(qb, klb, w2tb, outh, outhb);
    gemm_mfma<1><<<dim3(128, 4), 256, 0, stream>>>(outhb, woutb, nullptr, nullptr, nullptr, b_out, x, out);
}